// Round 1
// baseline (800.886 us; speedup 1.0000x reference)
//
#include <hip/hip_runtime.h>
#include <hip/hip_bf16.h>

typedef __attribute__((ext_vector_type(8))) short short8;
typedef __attribute__((ext_vector_type(4))) float f32x4;
typedef unsigned short u16;

#define DEV __device__ __forceinline__
#define MFMA(a, b, c) __builtin_amdgcn_mfma_f32_16x16x32_bf16(a, b, c, 0, 0, 0)

DEV u16 f2b(float f) {
    __hip_bfloat16 h = __float2bfloat16(f);
    return __builtin_bit_cast(unsigned short, h);
}

DEV void gl_lds16(const u16* g, u16* l) {
    __builtin_amdgcn_global_load_lds((const unsigned int*)g, (unsigned int*)l, 16, 0, 0);
}

// ---------------- cast x: fp32 -> bf16 ----------------
__global__ __launch_bounds__(256) void cast_bf16(const float* __restrict__ in, u16* __restrict__ out, int n) {
    int i = (blockIdx.x * 256 + threadIdx.x) * 4;
    if (i < n) {
        float4 v = *(const float4*)(in + i);
        ushort4 o;
        o.x = f2b(v.x); o.y = f2b(v.y); o.z = f2b(v.z); o.w = f2b(v.w);
        *(ushort4*)(out + i) = o;
    }
}

// ---------------- transpose + cast: W[R][C] fp32 -> Wt[C][R] bf16 ----------------
__global__ __launch_bounds__(256) void transpose_cast(const float* __restrict__ in, u16* __restrict__ out,
                                                      int R, int C) {
    __shared__ float t[32][33];
    int bx = blockIdx.x * 32;  // col tile
    int by = blockIdx.y * 32;  // row tile
    int tx = threadIdx.x, ty = threadIdx.y;  // (32, 8)
#pragma unroll
    for (int i = 0; i < 32; i += 8) t[ty + i][tx] = in[(size_t)(by + ty + i) * C + bx + tx];
    __syncthreads();
#pragma unroll
    for (int i = 0; i < 32; i += 8) out[(size_t)(bx + ty + i) * R + by + tx] = f2b(t[tx][ty + i]);
}

// ---------------- pack biases into one buffer ----------------
__global__ __launch_bounds__(256) void pack_bias(const float* __restrict__ bq, const float* __restrict__ bk,
                                                 const float* __restrict__ bv, const float* __restrict__ bo,
                                                 const float* __restrict__ b1, const float* __restrict__ b2,
                                                 float* __restrict__ out) {
    int i = blockIdx.x * 256 + threadIdx.x;
    if (i >= 9216) return;
    float v;
    if (i < 1024) v = bq[i];
    else if (i < 2048) v = bk[i - 1024];
    else if (i < 3072) v = bv[i - 2048];
    else if (i < 4096) v = bo[i - 3072];
    else if (i < 8192) v = b1[i - 4096];
    else v = b2[i - 8192];
    out[i] = v;
}

// ---------------- GEMM: C[M][N] = A[M][K] * Bt[N][K]^T + bias, optional GELU ----------------
// m97 structure: 128x128 tile, BK=32, 256 threads (4 waves, 2x2), global_load_lds width 16.
template <bool GELU, bool BF16OUT>
__global__ __launch_bounds__(256) void gemm_bt(const u16* __restrict__ A, const u16* __restrict__ B,
                                               const float* __restrict__ bias, float* __restrict__ cf,
                                               u16* __restrict__ cb, int M, int N, int K) {
    __shared__ __align__(16) u16 As[128 * 32];
    __shared__ __align__(16) u16 Bs[128 * 32];
    const int tid = threadIdx.x;
    const int wid = tid >> 6, lane = tid & 63;
    const int wr = wid >> 1, wc = wid & 1;
    const int m0 = blockIdx.x * 128, n0 = blockIdx.y * 128;
    const int r16 = lane & 15, g = lane >> 4;
    const int lrow = lane >> 2, lk = (lane & 3) * 8;

    f32x4 acc[4][4];
#pragma unroll
    for (int i = 0; i < 4; i++)
#pragma unroll
        for (int j = 0; j < 4; j++) acc[i][j] = (f32x4){0.f, 0.f, 0.f, 0.f};

    const u16* ga = A + (size_t)(m0 + wid * 32 + lrow) * K + lk;
    const u16* gb = B + (size_t)(n0 + wid * 32 + lrow) * K + lk;
    u16* lA0 = &As[(wid * 32) * 32];
    u16* lA1 = &As[(wid * 32 + 16) * 32];
    u16* lB0 = &Bs[(wid * 32) * 32];
    u16* lB1 = &Bs[(wid * 32 + 16) * 32];

    for (int kt = 0; kt < K; kt += 32) {
        gl_lds16(ga + kt, lA0);
        gl_lds16(ga + (size_t)16 * K + kt, lA1);
        gl_lds16(gb + kt, lB0);
        gl_lds16(gb + (size_t)16 * K + kt, lB1);
        __syncthreads();
        short8 af[4], bfr[4];
#pragma unroll
        for (int i = 0; i < 4; i++) af[i] = *(const short8*)&As[(wr * 64 + i * 16 + r16) * 32 + g * 8];
#pragma unroll
        for (int j = 0; j < 4; j++) bfr[j] = *(const short8*)&Bs[(wc * 64 + j * 16 + r16) * 32 + g * 8];
#pragma unroll
        for (int i = 0; i < 4; i++)
#pragma unroll
            for (int j = 0; j < 4; j++) acc[i][j] = MFMA(af[i], bfr[j], acc[i][j]);
        __syncthreads();
    }

#pragma unroll
    for (int i = 0; i < 4; i++) {
#pragma unroll
        for (int j = 0; j < 4; j++) {
#pragma unroll
            for (int r = 0; r < 4; r++) {
                int row = m0 + wr * 64 + i * 16 + g * 4 + r;
                int col = n0 + wc * 64 + j * 16 + r16;
                float v = acc[i][j][r] + bias[col];
                if (GELU) v = 0.5f * v * (1.0f + erff(v * 0.70710678118654752f));
                if (BF16OUT) cb[(size_t)row * N + col] = f2b(v);
                else cf[(size_t)row * N + col] = v;
            }
        }
    }
}

// ---------------- flash attention ----------------
// qkv: [8192][3072] bf16 (q | k | v, each head h at cols h*64). ctx: [8192][1024] bf16.
// Block: 4 waves, 64 q-rows (16/wave) for one (b,h). K-loop: 32 keys/iter.
__global__ __launch_bounds__(256) void attn_kernel(const u16* __restrict__ qkv, const int* __restrict__ mask,
                                                   u16* __restrict__ ctx) {
    const int tid = threadIdx.x, wid = tid >> 6, lane = tid & 63;
    const int r16 = lane & 15, g = lane >> 4;
    const int h = blockIdx.y, b = blockIdx.z;
    const size_t baserow = (size_t)b * 2048;
    const int q0 = blockIdx.x * 64 + wid * 16;

    __shared__ __align__(16) u16 Ks[32 * 64];
    __shared__ __align__(16) u16 Vt[64 * 40];   // [hd][key], padded rows of 40
    __shared__ __align__(16) u16 Ps[4][16 * 32];
    __shared__ float mb[32];

    short8 qf0, qf1;
    {
        const u16* qp = qkv + (baserow + q0 + r16) * 3072 + h * 64 + g * 8;
        qf0 = *(const short8*)qp;
        qf1 = *(const short8*)(qp + 32);
    }

    f32x4 o[4];
#pragma unroll
    for (int d = 0; d < 4; d++) o[d] = (f32x4){0.f, 0.f, 0.f, 0.f};
    float mrun[4], lrun[4];
#pragma unroll
    for (int j = 0; j < 4; j++) { mrun[j] = -1e30f; lrun[j] = 0.f; }

    const int srow = tid >> 3, scc = (tid & 7) * 8;
    const u16* kbase = qkv + (baserow + srow) * 3072 + 1024 + h * 64 + scc;
    const u16* vbase = kbase + 1024;

    for (int kt = 0; kt < 2048; kt += 32) {
        // stage K tile [32][64], V^T tile [64][40], mask bias
        short8 kv = *(const short8*)(kbase + (size_t)kt * 3072);
        short8 vv = *(const short8*)(vbase + (size_t)kt * 3072);
        *(short8*)&Ks[srow * 64 + scc] = kv;
#pragma unroll
        for (int e = 0; e < 8; e++) Vt[(scc + e) * 40 + srow] = (u16)vv[e];
        if (tid < 32) mb[tid] = mask[baserow + kt + tid] ? -4294967296.0f : 0.0f;
        __syncthreads();

        // S = Q K^T / 8 + maskbias  (two 16x16 key sub-tiles)
        float s0[4], s1[4];
        {
            f32x4 z0 = (f32x4){0.f, 0.f, 0.f, 0.f}, z1 = (f32x4){0.f, 0.f, 0.f, 0.f};
            short8 kb00 = *(const short8*)&Ks[r16 * 64 + g * 8];
            short8 kb01 = *(const short8*)&Ks[r16 * 64 + 32 + g * 8];
            short8 kb10 = *(const short8*)&Ks[(16 + r16) * 64 + g * 8];
            short8 kb11 = *(const short8*)&Ks[(16 + r16) * 64 + 32 + g * 8];
            z0 = MFMA(qf0, kb00, z0); z0 = MFMA(qf1, kb01, z0);
            z1 = MFMA(qf0, kb10, z1); z1 = MFMA(qf1, kb11, z1);
            float mb0 = mb[r16], mb1 = mb[16 + r16];
#pragma unroll
            for (int r = 0; r < 4; r++) { s0[r] = z0[r] * 0.125f + mb0; s1[r] = z1[r] * 0.125f + mb1; }
        }

        // online softmax (rows = g*4+j, cols spread over 16 lanes of group)
        float mt[4];
#pragma unroll
        for (int j = 0; j < 4; j++) mt[j] = fmaxf(s0[j], s1[j]);
#pragma unroll
        for (int m = 1; m < 16; m <<= 1)
#pragma unroll
            for (int j = 0; j < 4; j++) mt[j] = fmaxf(mt[j], __shfl_xor(mt[j], m, 64));
        float alpha[4];
#pragma unroll
        for (int j = 0; j < 4; j++) {
            float mn = fmaxf(mrun[j], mt[j]);
            alpha[j] = __expf(mrun[j] - mn);
            mrun[j] = mn;
        }
        float p0[4], p1[4], rs[4];
#pragma unroll
        for (int j = 0; j < 4; j++) {
            p0[j] = __expf(s0[j] - mrun[j]);
            p1[j] = __expf(s1[j] - mrun[j]);
            rs[j] = p0[j] + p1[j];
        }
#pragma unroll
        for (int m = 1; m < 16; m <<= 1)
#pragma unroll
            for (int j = 0; j < 4; j++) rs[j] += __shfl_xor(rs[j], m, 64);
#pragma unroll
        for (int j = 0; j < 4; j++) lrun[j] = lrun[j] * alpha[j] + rs[j];
#pragma unroll
        for (int d = 0; d < 4; d++) {
            o[d][0] *= alpha[0]; o[d][1] *= alpha[1]; o[d][2] *= alpha[2]; o[d][3] *= alpha[3];
        }

        // P (C-layout) -> LDS -> A-layout frags
        u16* pw = &Ps[wid][0];
#pragma unroll
        for (int j = 0; j < 4; j++) {
            int row = g * 4 + j;
            pw[row * 32 + r16] = f2b(p0[j]);
            pw[row * 32 + 16 + r16] = f2b(p1[j]);
        }
        asm volatile("s_waitcnt lgkmcnt(0)" ::: "memory");
        short8 pa = *(const short8*)&Ps[wid][r16 * 32 + g * 8];
#pragma unroll
        for (int d = 0; d < 4; d++) {
            short8 vb = *(const short8*)&Vt[(d * 16 + r16) * 40 + g * 8];
            o[d] = MFMA(pa, vb, o[d]);
        }
        __syncthreads();
    }

#pragma unroll
    for (int d = 0; d < 4; d++)
#pragma unroll
        for (int j = 0; j < 4; j++) {
            int row = g * 4 + j;
            float val = o[d][j] / lrun[j];
            ctx[(baserow + q0 + row) * 1024 + h * 64 + d * 16 + r16] = f2b(val);
        }
}

// ---------------- fused residual + layernorm ----------------
__global__ __launch_bounds__(256) void ln_kernel(const float* __restrict__ a, const float* __restrict__ res,
                                                 const float* __restrict__ gamma, const float* __restrict__ beta,
                                                 float* __restrict__ outf, u16* __restrict__ outb) {
    const int row = blockIdx.x, tid = threadIdx.x;
    const size_t base = (size_t)row * 1024 + tid * 4;
    float4 va = *(const float4*)(a + base);
    float4 vr = *(const float4*)(res + base);
    float x0 = va.x + vr.x, x1 = va.y + vr.y, x2 = va.z + vr.z, x3 = va.w + vr.w;
    float s = x0 + x1 + x2 + x3;
    float ss = x0 * x0 + x1 * x1 + x2 * x2 + x3 * x3;
#pragma unroll
    for (int m = 1; m < 64; m <<= 1) { s += __shfl_xor(s, m, 64); ss += __shfl_xor(ss, m, 64); }
    __shared__ float red[8];
    if ((tid & 63) == 0) { red[tid >> 6] = s; red[4 + (tid >> 6)] = ss; }
    __syncthreads();
    s = red[0] + red[1] + red[2] + red[3];
    ss = red[4] + red[5] + red[6] + red[7];
    float mu = s * (1.0f / 1024.0f);
    float var = ss * (1.0f / 1024.0f) - mu * mu;
    float rstd = rsqrtf(var + 1e-5f);
    float4 g4 = *(const float4*)(gamma + tid * 4);
    float4 b4 = *(const float4*)(beta + tid * 4);
    float y0 = (x0 - mu) * rstd * g4.x + b4.x;
    float y1 = (x1 - mu) * rstd * g4.y + b4.y;
    float y2 = (x2 - mu) * rstd * g4.z + b4.z;
    float y3 = (x3 - mu) * rstd * g4.w + b4.w;
    *(float4*)(outf + base) = make_float4(y0, y1, y2, y3);
    if (outb) {
        ushort4 ob;
        ob.x = f2b(y0); ob.y = f2b(y1); ob.z = f2b(y2); ob.w = f2b(y3);
        *(ushort4*)(outb + base) = ob;
    }
}

extern "C" void kernel_launch(void* const* d_in, const int* in_sizes, int n_in, void* d_out, int out_size,
                              void* d_ws, size_t ws_size, hipStream_t stream) {
    const float* x = (const float*)d_in[0];
    const int* mask = (const int*)d_in[1];
    const float* Wq = (const float*)d_in[2];
    const float* bq = (const float*)d_in[3];
    const float* Wk = (const float*)d_in[4];
    const float* bk = (const float*)d_in[5];
    const float* Wv = (const float*)d_in[6];
    const float* bv = (const float*)d_in[7];
    const float* Wo = (const float*)d_in[8];
    const float* bo = (const float*)d_in[9];
    const float* ln1s = (const float*)d_in[10];
    const float* ln1b = (const float*)d_in[11];
    const float* W1 = (const float*)d_in[12];
    const float* b1 = (const float*)d_in[13];
    const float* W2 = (const float*)d_in[14];
    const float* b2 = (const float*)d_in[15];
    const float* ln2s = (const float*)d_in[16];
    const float* ln2b = (const float*)d_in[17];
    float* out = (float*)d_out;
    char* ws = (char*)d_ws;

    const size_t MB = 1024 * 1024;
    u16* XB = (u16*)(ws + 0);                 // x bf16 [8192][1024], dead after qkv gemm
    u16* WTq = (u16*)(ws + 16 * MB);          // [Wq^T;Wk^T;Wv^T] contiguous = Bt[3072][1024]
    u16* WTk = WTq + 1024 * 1024;
    u16* WTv = WTk + 1024 * 1024;
    u16* WTo = WTv + 1024 * 1024;             // Wo^T [1024][1024]
    u16* WT1 = WTo + 1024 * 1024;             // W1^T [4096][1024]
    u16* WT2 = WT1 + 4096 * 1024;             // W2^T [1024][4096]
    float* BIAS = (float*)(ws + 40 * MB);     // [bq|bk|bv|bo|b1|b2] = 9216 floats
    u16* QKV = (u16*)(ws + 41 * MB);          // [8192][3072] bf16, dead after attention
    u16* CTX = (u16*)(ws + 0);                // [8192][1024] bf16 (reuse XB)
    float* ATT = (float*)(ws + 41 * MB);      // attn_out fp32 (reuse QKV), dead after ln1
    float* Hbuf = (float*)(ws + 73 * MB);     // h fp32
    u16* HB = (u16*)(ws + 105 * MB);          // h bf16
    u16* MLP1 = (u16*)(ws + 121 * MB);        // [8192][4096] bf16
    float* MLP2 = (float*)(ws + 41 * MB);     // mlp2 fp32 (reuse ATT)

    dim3 tb(32, 8);
    cast_bf16<<<8192, 256, 0, stream>>>(x, XB, 8192 * 1024);
    transpose_cast<<<dim3(32, 32), tb, 0, stream>>>(Wq, WTq, 1024, 1024);
    transpose_cast<<<dim3(32, 32), tb, 0, stream>>>(Wk, WTk, 1024, 1024);
    transpose_cast<<<dim3(32, 32), tb, 0, stream>>>(Wv, WTv, 1024, 1024);
    transpose_cast<<<dim3(32, 32), tb, 0, stream>>>(Wo, WTo, 1024, 1024);
    transpose_cast<<<dim3(128, 32), tb, 0, stream>>>(W1, WT1, 1024, 4096);
    transpose_cast<<<dim3(32, 128), tb, 0, stream>>>(W2, WT2, 4096, 1024);
    pack_bias<<<36, 256, 0, stream>>>(bq, bk, bv, bo, b1, b2, BIAS);

    // QKV projection: [8192][3072]
    gemm_bt<false, true><<<dim3(64, 24), 256, 0, stream>>>(XB, WTq, BIAS, nullptr, QKV, 8192, 3072, 1024);
    // attention
    attn_kernel<<<dim3(32, 16, 4), 256, 0, stream>>>(QKV, mask, CTX);
    // output projection (fp32 out)
    gemm_bt<false, false><<<dim3(64, 8), 256, 0, stream>>>(CTX, WTo, BIAS + 3072, ATT, nullptr, 8192, 1024, 1024);
    // h = LN(attn_out + x)
    ln_kernel<<<8192, 256, 0, stream>>>(ATT, x, ln1s, ln1b, Hbuf, HB);
    // mlp1 = gelu(h @ W1 + b1)  (bf16 out)
    gemm_bt<true, true><<<dim3(64, 32), 256, 0, stream>>>(HB, WT1, BIAS + 4096, nullptr, MLP1, 8192, 4096, 1024);
    // mlp2 = mlp1 @ W2 + b2 (fp32 out)
    gemm_bt<false, false><<<dim3(64, 8), 256, 0, stream>>>(MLP1, WT2, BIAS + 8192, MLP2, nullptr, 8192, 1024, 4096);
    // out = LN(mlp2 + h)
    ln_kernel<<<8192, 256, 0, stream>>>(MLP2, Hbuf, ln2s, ln2b, out, nullptr);
}

// Round 3
// 554.538 us; speedup vs baseline: 1.4442x; 1.4442x over previous
//
#include <hip/hip_runtime.h>
#include <hip/hip_bf16.h>

typedef __attribute__((ext_vector_type(8))) short short8;
typedef __attribute__((ext_vector_type(4))) short s16x4;
typedef __attribute__((ext_vector_type(4))) float f32x4;
typedef unsigned short u16;

#define DEV __device__ __forceinline__
#define MFMA32(a, b, c) __builtin_amdgcn_mfma_f32_16x16x32_bf16(a, b, c, 0, 0, 0)
#define MFMA16(a, b, c) __builtin_amdgcn_mfma_f32_16x16x16bf16_1k(a, b, c, 0, 0, 0)

DEV u16 f2b(float f) {
    __hip_bfloat16 h = __float2bfloat16(f);
    return __builtin_bit_cast(unsigned short, h);
}

DEV void gl_lds16(const u16* g, u16* l) {
    __builtin_amdgcn_global_load_lds((const unsigned int*)g, (unsigned int*)l, 16, 0, 0);
}

// ---------------- cast x: fp32 -> bf16 ----------------
__global__ __launch_bounds__(256) void cast_bf16(const float* __restrict__ in, u16* __restrict__ out, int n) {
    int i = (blockIdx.x * 256 + threadIdx.x) * 4;
    if (i < n) {
        float4 v = *(const float4*)(in + i);
        ushort4 o;
        o.x = f2b(v.x); o.y = f2b(v.y); o.z = f2b(v.z); o.w = f2b(v.w);
        *(ushort4*)(out + i) = o;
    }
}

// ---------------- transpose + cast: W[R][C] fp32 -> Wt[C][R] bf16 ----------------
__global__ __launch_bounds__(256) void transpose_cast(const float* __restrict__ in, u16* __restrict__ out,
                                                      int R, int C) {
    __shared__ float t[32][33];
    int bx = blockIdx.x * 32;  // col tile
    int by = blockIdx.y * 32;  // row tile
    int tx = threadIdx.x, ty = threadIdx.y;  // (32, 8)
#pragma unroll
    for (int i = 0; i < 32; i += 8) t[ty + i][tx] = in[(size_t)(by + ty + i) * C + bx + tx];
    __syncthreads();
#pragma unroll
    for (int i = 0; i < 32; i += 8) out[(size_t)(bx + ty + i) * R + by + tx] = f2b(t[tx][ty + i]);
}

// ---------------- pack biases into one buffer ----------------
__global__ __launch_bounds__(256) void pack_bias(const float* __restrict__ bq, const float* __restrict__ bk,
                                                 const float* __restrict__ bv, const float* __restrict__ bo,
                                                 const float* __restrict__ b1, const float* __restrict__ b2,
                                                 float* __restrict__ out) {
    int i = blockIdx.x * 256 + threadIdx.x;
    if (i >= 9216) return;
    float v;
    if (i < 1024) v = bq[i];
    else if (i < 2048) v = bk[i - 1024];
    else if (i < 3072) v = bv[i - 2048];
    else if (i < 4096) v = bo[i - 3072];
    else if (i < 8192) v = b1[i - 4096];
    else v = b2[i - 8192];
    out[i] = v;
}

// ---------------- GEMM: C[M][N] = A[M][K] * Bt[N][K]^T + bias, optional GELU ----------------
template <bool GELU, bool BF16OUT>
__global__ __launch_bounds__(256) void gemm_bt(const u16* __restrict__ A, const u16* __restrict__ B,
                                               const float* __restrict__ bias, float* __restrict__ cf,
                                               u16* __restrict__ cb, int M, int N, int K) {
    __shared__ __align__(16) u16 As[128 * 32];
    __shared__ __align__(16) u16 Bs[128 * 32];
    const int tid = threadIdx.x;
    const int wid = tid >> 6, lane = tid & 63;
    const int wr = wid >> 1, wc = wid & 1;
    const int m0 = blockIdx.x * 128, n0 = blockIdx.y * 128;
    const int r16 = lane & 15, g = lane >> 4;
    const int lrow = lane >> 2, lk = (lane & 3) * 8;

    f32x4 acc[4][4];
#pragma unroll
    for (int i = 0; i < 4; i++)
#pragma unroll
        for (int j = 0; j < 4; j++) acc[i][j] = (f32x4){0.f, 0.f, 0.f, 0.f};

    const u16* ga = A + (size_t)(m0 + wid * 32 + lrow) * K + lk;
    const u16* gb = B + (size_t)(n0 + wid * 32 + lrow) * K + lk;
    u16* lA0 = &As[(wid * 32) * 32];
    u16* lA1 = &As[(wid * 32 + 16) * 32];
    u16* lB0 = &Bs[(wid * 32) * 32];
    u16* lB1 = &Bs[(wid * 32 + 16) * 32];

    for (int kt = 0; kt < K; kt += 32) {
        gl_lds16(ga + kt, lA0);
        gl_lds16(ga + (size_t)16 * K + kt, lA1);
        gl_lds16(gb + kt, lB0);
        gl_lds16(gb + (size_t)16 * K + kt, lB1);
        __syncthreads();
        short8 af[4], bfr[4];
#pragma unroll
        for (int i = 0; i < 4; i++) af[i] = *(const short8*)&As[(wr * 64 + i * 16 + r16) * 32 + g * 8];
#pragma unroll
        for (int j = 0; j < 4; j++) bfr[j] = *(const short8*)&Bs[(wc * 64 + j * 16 + r16) * 32 + g * 8];
#pragma unroll
        for (int i = 0; i < 4; i++)
#pragma unroll
            for (int j = 0; j < 4; j++) acc[i][j] = MFMA32(af[i], bfr[j], acc[i][j]);
        __syncthreads();
    }

#pragma unroll
    for (int i = 0; i < 4; i++) {
#pragma unroll
        for (int j = 0; j < 4; j++) {
#pragma unroll
            for (int r = 0; r < 4; r++) {
                int row = m0 + wr * 64 + i * 16 + g * 4 + r;
                int col = n0 + wc * 64 + j * 16 + r16;
                float v = acc[i][j][r] + bias[col];
                if (GELU) v = 0.5f * v * (1.0f + erff(v * 0.70710678118654752f));
                if (BF16OUT) cb[(size_t)row * N + col] = f2b(v);
                else cf[(size_t)row * N + col] = v;
            }
        }
    }
}

// ---------------- flash attention (swapped-QK^T, KBLK=64) ----------------
// qkv: [8192][3072] bf16 (q|k|v; head h at col h*64). ctx: [8192][1024] bf16.
// Block = 4 waves; wave wid owns 16 q-rows (q = q0 + wid*16 + (lane&15)).
// S^T = mfma32(K, Q): lane holds P[key = t*16 + 4g + j][q = r16].
// PV:  O^T = mfma16(V^T_frag(tr_read), P_frag(registers)).
__global__ __launch_bounds__(256) void attn_kernel(const u16* __restrict__ qkv, const int* __restrict__ mask,
                                                   u16* __restrict__ ctx) {
    const int tid = threadIdx.x, wid = tid >> 6, lane = tid & 63;
    const int r16 = lane & 15, g = lane >> 4;
    const int h = blockIdx.y, b = blockIdx.z;
    const size_t baserow = (size_t)b * 2048;
    const int q0 = blockIdx.x * 64;

    // Ks: [64 keys][64 d] u16, 16B-chunk XOR swizzle (chunk ^= row&7).
    // Vs: 16 subtiles of [16 keys][16 d] row-major (tile T = t*4 + dt), linear for tr_read.
    __shared__ __align__(16) u16 Ks[64 * 64];
    __shared__ __align__(16) u16 Vs[64 * 64];
    __shared__ __align__(16) float mb[64];

    const float SCALE = 0.18033688011112042f;   // 0.125 * log2(e)
    const float MNEG = -6.196328018e9f;         // -2^32 * log2(e)

    // Q fragments (B-operand): Q[q][8g+e] and Q[q][32+8g+e]
    short8 qf0, qf1;
    {
        const u16* qp = qkv + (baserow + q0 + wid * 16 + r16) * 3072 + h * 64 + g * 8;
        qf0 = *(const short8*)qp;
        qf1 = *(const short8*)(qp + 32);
    }

    // staging addresses (wave wid stages keys wid*16..wid*16+15)
    const int L = lane;
    const int kchunk = (L & 7) ^ (L >> 3);          // inverse-swizzled global chunk
    const u16* kg0 = qkv + (baserow + wid * 16 + (L >> 3)) * 3072 + 1024 + h * 64 + kchunk * 8;
    const u16* kg1 = kg0 + (size_t)8 * 3072;        // rows +8
    u16* kl0 = &Ks[wid * 1024];
    u16* kl1 = &Ks[wid * 1024 + 512];
    const u16* vg0 = qkv + (baserow + wid * 16 + ((L & 31) >> 1)) * 3072 + 2048 + h * 64
                     + ((L >> 5) * 16 + (L & 1) * 8);
    const u16* vg1 = vg0 + 32;                      // dt += 2
    u16* vl0 = &Vs[wid * 1024];
    u16* vl1 = &Vs[wid * 1024 + 512];
    // per-lane tr_read address: lane l, elem j reads lds[(l&15) + j*16 + (l>>4)*64] (u16)
    const unsigned vaddr = (unsigned)(unsigned long long)&Vs[0] + (unsigned)(r16 * 2 + g * 128);

    f32x4 Ot[4];
#pragma unroll
    for (int dt = 0; dt < 4; dt++) Ot[dt] = (f32x4){0.f, 0.f, 0.f, 0.f};
    float mrun = -1e30f, lrun = 0.f;

    for (int kt = 0; kt < 2048; kt += 64) {
        const size_t go = (size_t)kt * 3072;
        gl_lds16(kg0 + go, kl0);
        gl_lds16(kg1 + go, kl1);
        gl_lds16(vg0 + go, vl0);
        gl_lds16(vg1 + go, vl1);
        if (tid < 64) mb[tid] = mask[baserow + kt + tid] ? MNEG : 0.0f;
        __syncthreads();

        // S^T tiles: z[t] = K_tile(t) x Q  -> lane holds S[t*16+4g+j][q=r16]
        f32x4 z[4];
#pragma unroll
        for (int t = 0; t < 4; t++) {
            const int row = t * 16 + r16;
            const int sw = row & 7;
            short8 a0 = *(const short8*)&Ks[row * 64 + ((g ^ sw) * 8)];
            short8 a1 = *(const short8*)&Ks[row * 64 + (((4 + g) ^ sw) * 8)];
            f32x4 zz = (f32x4){0.f, 0.f, 0.f, 0.f};
            zz = MFMA32(a0, qf0, zz);
            zz = MFMA32(a1, qf1, zz);
            z[t] = zz;
        }

        // s' = z*scale + maskbias  (log2 domain)
        f32x4 sv[4];
#pragma unroll
        for (int t = 0; t < 4; t++) {
            f32x4 mbv = *(const f32x4*)&mb[t * 16 + g * 4];
            sv[t] = z[t] * SCALE + mbv;
        }

        // row max (16 in-lane + 2 shfl across g-groups)
        float pmax = sv[0][0];
#pragma unroll
        for (int t = 0; t < 4; t++)
#pragma unroll
            for (int j = 0; j < 4; j++) pmax = fmaxf(pmax, sv[t][j]);
        pmax = fmaxf(pmax, __shfl_xor(pmax, 16));
        pmax = fmaxf(pmax, __shfl_xor(pmax, 32));

        // defer-max (THR = 11.5 in log2 domain ~= 8 nats)
        if (!__all(pmax - mrun <= 11.5f)) {
            float mnew = fmaxf(mrun, pmax);
            float alpha = exp2f(mrun - mnew);
            mrun = mnew;
            lrun *= alpha;
#pragma unroll
            for (int dt = 0; dt < 4; dt++) Ot[dt] *= alpha;
        }

        // p = 2^(s'-m), pack to bf16 B-frags, accumulate l
        s16x4 pb[4];
        float rs = 0.f;
#pragma unroll
        for (int t = 0; t < 4; t++) {
            float p0 = exp2f(sv[t][0] - mrun);
            float p1 = exp2f(sv[t][1] - mrun);
            float p2 = exp2f(sv[t][2] - mrun);
            float p3 = exp2f(sv[t][3] - mrun);
            rs += (p0 + p1) + (p2 + p3);
            s16x4 pk;
            pk[0] = (short)f2b(p0); pk[1] = (short)f2b(p1);
            pk[2] = (short)f2b(p2); pk[3] = (short)f2b(p3);
            pb[t] = pk;
        }
        rs += __shfl_xor(rs, 16);
        rs += __shfl_xor(rs, 32);
        lrun += rs;

        // PV: O^T[dt] += V^T_frag(t,dt) x P_frag(t)
        s16x4 vf[4][4];
#pragma unroll
        for (int t = 0; t < 4; t++)
#pragma unroll
            for (int dt = 0; dt < 4; dt++)
                asm volatile("ds_read_b64_tr_b16 %0, %1"
                             : "=v"(vf[t][dt])
                             : "v"(vaddr + (unsigned)((t * 4 + dt) * 512)));
        asm volatile("s_waitcnt lgkmcnt(0)" ::: "memory");
        __builtin_amdgcn_sched_barrier(0);
#pragma unroll
        for (int t = 0; t < 4; t++)
#pragma unroll
            for (int dt = 0; dt < 4; dt++) Ot[dt] = MFMA16(vf[t][dt], pb[t], Ot[dt]);
        __syncthreads();
    }

    // write O: lane holds O^T[d = dt*16 + 4g + j][q = r16]
    const float rl = 1.0f / lrun;
    u16* cp = ctx + (baserow + q0 + wid * 16 + r16) * 1024 + h * 64 + g * 4;
#pragma unroll
    for (int dt = 0; dt < 4; dt++) {
        ushort4 o4;
        o4.x = f2b(Ot[dt][0] * rl);
        o4.y = f2b(Ot[dt][1] * rl);
        o4.z = f2b(Ot[dt][2] * rl);
        o4.w = f2b(Ot[dt][3] * rl);
        *(ushort4*)(cp + dt * 16) = o4;
    }
}

// ---------------- fused residual + layernorm ----------------
__global__ __launch_bounds__(256) void ln_kernel(const float* __restrict__ a, const float* __restrict__ res,
                                                 const float* __restrict__ gamma, const float* __restrict__ beta,
                                                 float* __restrict__ outf, u16* __restrict__ outb) {
    const int row = blockIdx.x, tid = threadIdx.x;
    const size_t base = (size_t)row * 1024 + tid * 4;
    float4 va = *(const float4*)(a + base);
    float4 vr = *(const float4*)(res + base);
    float x0 = va.x + vr.x, x1 = va.y + vr.y, x2 = va.z + vr.z, x3 = va.w + vr.w;
    float s = x0 + x1 + x2 + x3;
    float ss = x0 * x0 + x1 * x1 + x2 * x2 + x3 * x3;
#pragma unroll
    for (int m = 1; m < 64; m <<= 1) { s += __shfl_xor(s, m, 64); ss += __shfl_xor(ss, m, 64); }
    __shared__ float red[8];
    if ((tid & 63) == 0) { red[tid >> 6] = s; red[4 + (tid >> 6)] = ss; }
    __syncthreads();
    s = red[0] + red[1] + red[2] + red[3];
    ss = red[4] + red[5] + red[6] + red[7];
    float mu = s * (1.0f / 1024.0f);
    float var = ss * (1.0f / 1024.0f) - mu * mu;
    float rstd = rsqrtf(var + 1e-5f);
    float4 g4 = *(const float4*)(gamma + tid * 4);
    float4 b4 = *(const float4*)(beta + tid * 4);
    float y0 = (x0 - mu) * rstd * g4.x + b4.x;
    float y1 = (x1 - mu) * rstd * g4.y + b4.y;
    float y2 = (x2 - mu) * rstd * g4.z + b4.z;
    float y3 = (x3 - mu) * rstd * g4.w + b4.w;
    *(float4*)(outf + base) = make_float4(y0, y1, y2, y3);
    if (outb) {
        ushort4 ob;
        ob.x = f2b(y0); ob.y = f2b(y1); ob.z = f2b(y2); ob.w = f2b(y3);
        *(ushort4*)(outb + base) = ob;
    }
}

extern "C" void kernel_launch(void* const* d_in, const int* in_sizes, int n_in, void* d_out, int out_size,
                              void* d_ws, size_t ws_size, hipStream_t stream) {
    const float* x = (const float*)d_in[0];
    const int* mask = (const int*)d_in[1];
    const float* Wq = (const float*)d_in[2];
    const float* bq = (const float*)d_in[3];
    const float* Wk = (const float*)d_in[4];
    const float* bk = (const float*)d_in[5];
    const float* Wv = (const float*)d_in[6];
    const float* bv = (const float*)d_in[7];
    const float* Wo = (const float*)d_in[8];
    const float* bo = (const float*)d_in[9];
    const float* ln1s = (const float*)d_in[10];
    const float* ln1b = (const float*)d_in[11];
    const float* W1 = (const float*)d_in[12];
    const float* b1 = (const float*)d_in[13];
    const float* W2 = (const float*)d_in[14];
    const float* b2 = (const float*)d_in[15];
    const float* ln2s = (const float*)d_in[16];
    const float* ln2b = (const float*)d_in[17];
    float* out = (float*)d_out;
    char* ws = (char*)d_ws;

    const size_t MB = 1024 * 1024;
    u16* XB = (u16*)(ws + 0);                 // x bf16 [8192][1024], dead after qkv gemm
    u16* WTq = (u16*)(ws + 16 * MB);          // [Wq^T;Wk^T;Wv^T] = Bt[3072][1024]
    u16* WTk = WTq + 1024 * 1024;
    u16* WTv = WTk + 1024 * 1024;
    u16* WTo = WTv + 1024 * 1024;             // Wo^T [1024][1024]
    u16* WT1 = WTo + 1024 * 1024;             // W1^T [4096][1024]
    u16* WT2 = WT1 + 4096 * 1024;             // W2^T [1024][4096]
    float* BIAS = (float*)(ws + 40 * MB);     // [bq|bk|bv|bo|b1|b2] = 9216 floats
    u16* QKV = (u16*)(ws + 41 * MB);          // [8192][3072] bf16, dead after attention
    u16* CTX = (u16*)(ws + 0);                // [8192][1024] bf16 (reuse XB)
    float* ATT = (float*)(ws + 41 * MB);      // attn_out fp32 (reuse QKV), dead after ln1
    float* Hbuf = (float*)(ws + 73 * MB);     // h fp32
    u16* HB = (u16*)(ws + 105 * MB);          // h bf16
    u16* MLP1 = (u16*)(ws + 121 * MB);        // [8192][4096] bf16
    float* MLP2 = (float*)(ws + 41 * MB);     // mlp2 fp32 (reuse ATT)

    dim3 tb(32, 8);
    cast_bf16<<<8192, 256, 0, stream>>>(x, XB, 8192 * 1024);
    transpose_cast<<<dim3(32, 32), tb, 0, stream>>>(Wq, WTq, 1024, 1024);
    transpose_cast<<<dim3(32, 32), tb, 0, stream>>>(Wk, WTk, 1024, 1024);
    transpose_cast<<<dim3(32, 32), tb, 0, stream>>>(Wv, WTv, 1024, 1024);
    transpose_cast<<<dim3(32, 32), tb, 0, stream>>>(Wo, WTo, 1024, 1024);
    transpose_cast<<<dim3(128, 32), tb, 0, stream>>>(W1, WT1, 1024, 4096);
    transpose_cast<<<dim3(32, 128), tb, 0, stream>>>(W2, WT2, 4096, 1024);
    pack_bias<<<36, 256, 0, stream>>>(bq, bk, bv, bo, b1, b2, BIAS);

    gemm_bt<false, true><<<dim3(64, 24), 256, 0, stream>>>(XB, WTq, BIAS, nullptr, QKV, 8192, 3072, 1024);
    attn_kernel<<<dim3(32, 16, 4), 256, 0, stream>>>(QKV, mask, CTX);
    gemm_bt<false, false><<<dim3(64, 8), 256, 0, stream>>>(CTX, WTo, BIAS + 3072, ATT, nullptr, 8192, 1024, 1024);
    ln_kernel<<<8192, 256, 0, stream>>>(ATT, x, ln1s, ln1b, Hbuf, HB);
    gemm_bt<true, true><<<dim3(64, 32), 256, 0, stream>>>(HB, WT1, BIAS + 4096, nullptr, MLP1, 8192, 4096, 1024);
    gemm_bt<false, false><<<dim3(64, 8), 256, 0, stream>>>(MLP1, WT2, BIAS + 8192, MLP2, nullptr, 8192, 1024, 4096);
    ln_kernel<<<8192, 256, 0, stream>>>(MLP2, Hbuf, ln2s, ln2b, out, nullptr);
}